// Round 13
// baseline (148.028 us; speedup 1.0000x reference)
//
#include <hip/hip_runtime.h>

typedef float f4 __attribute__((ext_vector_type(4)));

#define BB 1024
#define SS 192
#define DD 512
#define NUM_LAYERS 3
#define LN_EPS 1e-5f
#define NBLK 2048
#define NWAVES (NBLK * 4)
#define RPB (SS * (DD / 4))              // f4 slots per batch row-block

// ---------------- prep: add_tab + start[] --------------------------------
__global__ __launch_bounds__(256) void prep_kernel(
    const int* __restrict__ mask,
    const float* __restrict__ item_pos,
    const float* __restrict__ layer_emb,
    const float* __restrict__ decay,
    float* __restrict__ add_tab,
    int* __restrict__ start)
{
    const int tid = threadIdx.x;
    if (blockIdx.x < SS) {
        const int p = blockIdx.x;
        if (tid < DD / 4) {
            const int item = p / NUM_LAYERS;
            const int layer = p - item * NUM_LAYERS;
            const f4 iv = reinterpret_cast<const f4*>(item_pos + item * DD)[tid];
            const f4 lv = reinterpret_cast<const f4*>(layer_emb + layer * DD)[tid];
            const f4 dv = reinterpret_cast<const f4*>(decay + item * DD)[tid];
            reinterpret_cast<f4*>(add_tab + p * DD)[tid] = iv + lv + dv;
        }
        return;
    }
    const int b = (blockIdx.x - SS) * 4 + (tid >> 6);
    const int lane = tid & 63;
    if (b < BB) {
        const int* m = mask + b * SS;
        const unsigned long long b0 = __ballot(m[lane] > 0);
        const unsigned long long b1 = __ballot(m[lane + 64] > 0);
        const unsigned long long b2 = __ballot(m[lane + 128] > 0);
        int idx;
        if (b0)      idx = __ffsll(b0) - 1;
        else if (b1) idx = 64 + __ffsll(b1) - 1;
        else if (b2) idx = 128 + __ffsll(b2) - 1;
        else         idx = SS;
        if (lane == 0) start[b] = idx;
    }
}

// ---------------- scan: content-row prefix P and zero-f4 prefix Z ---------
__global__ __launch_bounds__(1024) void scan_kernel(
    const int* __restrict__ start,
    int* __restrict__ P, int* __restrict__ Z, int* __restrict__ tot)
{
    __shared__ int sh[1024];
    const int t = threadIdx.x;
    const int st = start[t];

    const int cnt = SS - st;                    // content rows of batch t
    sh[t] = cnt;
    __syncthreads();
    #pragma unroll
    for (int off = 1; off < 1024; off <<= 1) {
        const int u = (t >= off) ? sh[t - off] : 0;
        __syncthreads();
        sh[t] += u;
        __syncthreads();
    }
    P[t] = sh[t] - cnt;
    if (t == 1023) { P[1024] = sh[1023]; tot[0] = sh[1023]; }
    __syncthreads();

    const int zc = st * (DD / 4);               // zero f4 slots of batch t
    sh[t] = zc;
    __syncthreads();
    #pragma unroll
    for (int off = 1; off < 1024; off <<= 1) {
        const int u = (t >= off) ? sh[t - off] : 0;
        __syncthreads();
        sh[t] += u;
        __syncthreads();
    }
    Z[t] = sh[t] - zc;
    if (t == 1023) { Z[1024] = sh[1023]; tot[1] = sh[1023]; }
}

template <int CTRL>
__device__ __forceinline__ float dpp_x(float v) {
    return __uint_as_float((unsigned)__builtin_amdgcn_update_dpp(
            0, (int)__float_as_uint(v), CTRL, 0xF, 0xF, true));
}
__device__ __forceinline__ float swz16(float v) {
    return __uint_as_float((unsigned)__builtin_amdgcn_ds_swizzle(
            (int)__float_as_uint(v), 0x401f));
}
__device__ __forceinline__ float bper32(float v, int xaddr32) {
    return __uint_as_float((unsigned)__builtin_amdgcn_ds_bpermute(
            xaddr32, (int)__float_as_uint(v)));
}

__device__ __forceinline__ void wave_allreduce2(float& v0, float& v1, int xaddr32) {
    v0 += dpp_x<0xB1>(v0);  v1 += dpp_x<0xB1>(v1);
    v0 += dpp_x<0x4E>(v0);  v1 += dpp_x<0x4E>(v1);
    v0 += dpp_x<0x141>(v0); v1 += dpp_x<0x141>(v1);
    v0 += dpp_x<0x140>(v0); v1 += dpp_x<0x140>(v1);
    v0 += swz16(v0);        v1 += swz16(v1);
    v0 += bper32(v0, xaddr32); v1 += bper32(v1, xaddr32);
}

// ---------------- main: balanced zero windows + content windows -----------
__global__ __launch_bounds__(256) void main_kernel(
    const float* __restrict__ tok,
    const float* __restrict__ add_tab,
    const float* __restrict__ lnw,
    const float* __restrict__ lnb,
    const int* __restrict__ P,
    const int* __restrict__ Z,
    const int* __restrict__ tot,
    float* __restrict__ out)
{
    const int tid = threadIdx.x;

    // ---- phase 1: equal contiguous window of the flat padded-f4 space ----
    {
        const int ZT = tot[1];
        const int zq = (ZT + NBLK - 1) / NBLK;
        int g = blockIdx.x * zq;
        const int ze0 = g + zq;
        const int ze = ze0 < ZT ? ze0 : ZT;
        if (g < ze) {
            int lo = 0, hi = BB;
            while (lo < hi) {                    // largest b with Z[b] <= g
                const int mid = (lo + hi + 1) >> 1;
                if (Z[mid] <= g) lo = mid; else hi = mid - 1;
            }
            int b = lo;
            const f4 zv = {0.f, 0.f, 0.f, 0.f};
            while (g < ze) {
                int zb1 = Z[b + 1];
                while (g >= zb1) { ++b; zb1 = Z[b + 1]; }
                const int zb = Z[b];
                const int lim = ze < zb1 ? ze : zb1;
                f4* dst = reinterpret_cast<f4*>(out) + (size_t)b * RPB + (g - zb);
                const int n = lim - g;
                for (int i = tid; i < n; i += 256)
                    dst[i] = zv;
                g = lim;
            }
        }
    }

    // ---- phase 2: equal contiguous window of the flat content-row space --
    const int wid = tid >> 6;
    const int lane = tid & 63;
    const int l0 = lane;
    const int l1 = lane + 64;
    const int xaddr32 = (lane ^ 32) << 2;

    const f4 w0 = reinterpret_cast<const f4*>(lnw)[l0];
    const f4 w1 = reinterpret_cast<const f4*>(lnw)[l1];
    const f4 c0 = reinterpret_cast<const f4*>(lnb)[l0];
    const f4 c1 = reinterpret_cast<const f4*>(lnb)[l1];

    const int wave = blockIdx.x * 4 + wid;
    const int Nc = tot[0];
    const int nq = (Nc + NWAVES - 1) / NWAVES;
    const int gs = wave * nq;
    if (gs >= Nc) return;
    const int ge = (gs + nq < Nc) ? gs + nq : Nc;

    int lo = 0, hi = BB;
    while (lo < hi) {                            // largest b with P[b] <= gs
        const int mid = (lo + hi + 1) >> 1;
        if (P[mid] <= gs) lo = mid; else hi = mid - 1;
    }
    int b = lo;
    int pb = P[b], pb1 = P[b + 1];

    #pragma unroll 1
    for (int g = gs; g < ge; ++g) {
        if (g >= pb1) {
            do { ++b; pb1 = P[b + 1]; } while (g >= pb1);
            pb = P[b];
        }
        const int pos = g - pb;
        const int st = SS - (pb1 - pb);
        const int row = b * SS + st + pos;

        const f4* x4 = reinterpret_cast<const f4*>(tok + (size_t)row * DD);
        const f4 xv0 = x4[l0];
        const f4 xv1 = x4[l1];

        const f4* a4 = reinterpret_cast<const f4*>(add_tab + pos * DD);
        const f4 y0 = xv0 + a4[l0];
        const f4 y1 = xv1 + a4[l1];

        float sum = (y0.x + y0.y) + (y0.z + y0.w)
                  + (y1.x + y1.y) + (y1.z + y1.w);
        const f4 q0 = y0 * y0;
        const f4 q1 = y1 * y1;
        float sq = (q0.x + q0.y) + (q0.z + q0.w)
                 + (q1.x + q1.y) + (q1.z + q1.w);

        wave_allreduce2(sum, sq, xaddr32);

        const float mu  = sum * (1.0f / DD);
        const float var = sq * (1.0f / DD) - mu * mu;
        const float inv = rsqrtf(var + LN_EPS);

        f4* o4 = reinterpret_cast<f4*>(out + (size_t)row * DD);
        o4[l0] = (y0 - mu) * inv * w0 + c0;
        o4[l1] = (y1 - mu) * inv * w1 + c1;
    }
}

extern "C" void kernel_launch(void* const* d_in, const int* in_sizes, int n_in,
                              void* d_out, int out_size, void* d_ws, size_t ws_size,
                              hipStream_t stream) {
    const float* tok       = (const float*)d_in[0];   // (B,S,D)
    const int*   mask      = (const int*)d_in[1];     // (B,S)
    const float* item_pos  = (const float*)d_in[2];   // (64,D)
    const float* layer_emb = (const float*)d_in[3];   // (3,D)
    const float* decay     = (const float*)d_in[4];   // (64,D)
    const float* lnw       = (const float*)d_in[5];   // (D,)
    const float* lnb       = (const float*)d_in[6];   // (D,)
    float* out = (float*)d_out;

    // workspace: [tot 2i pad 256B][add_tab SS*DD f32][start BB i][P BB+1 i][Z BB+1 i]
    int*   tot     = (int*)d_ws;
    float* add_tab = (float*)((char*)d_ws + 256);
    int*   start   = (int*)((char*)add_tab + (size_t)SS * DD * sizeof(float));
    int*   P       = start + BB;
    int*   Z       = P + BB + 1;

    prep_kernel<<<SS + 256, 256, 0, stream>>>(mask, item_pos, layer_emb, decay,
                                              add_tab, start);
    scan_kernel<<<1, 1024, 0, stream>>>(start, P, Z, tot);
    main_kernel<<<NBLK, 256, 0, stream>>>(tok, add_tab, lnw, lnb, P, Z, tot, out);
}